// Round 4
// baseline (276.720 us; speedup 1.0000x reference)
//
#include <hip/hip_runtime.h>
#include <cstdint>
#include <cstddef>

typedef unsigned short u16;
typedef __attribute__((ext_vector_type(8))) short bf16x8;
typedef __attribute__((ext_vector_type(16))) float f32x16;
typedef __attribute__((ext_vector_type(8))) unsigned short u16x8;

#define T_TOK 8192
#define H_DIM 1024
#define F_DIM 4096
#define E_NUM 8
#define CAP (T_TOK / E_NUM)

template <int I> struct IC { static constexpr int v = I; };

__device__ __forceinline__ u16 f2bf(float f) {
  union { float f; uint32_t u; } v; v.f = f;
  uint32_t r = v.u + 0x7FFFu + ((v.u >> 16) & 1u);
  return (u16)(r >> 16);
}

__device__ __forceinline__ float gelu_tanh(float x) {
  float z2 = 1.5957691216057308f * (x + 0.044715f * x * x * x);
  float e = __expf(z2);
  return x * (1.0f - 1.0f / (e + 1.0f));
}

__device__ __forceinline__ void async_copy16(const void* gsrc, void* ldst) {
  __builtin_amdgcn_global_load_lds(
      (const __attribute__((address_space(1))) uint32_t*)gsrc,
      (__attribute__((address_space(3))) uint32_t*)ldst, 16, 0, 0);
}

__device__ __forceinline__ void wgbar() {
  asm volatile("" ::: "memory");
  __builtin_amdgcn_s_barrier();
  asm volatile("" ::: "memory");
}

template <int N> __device__ __forceinline__ void vm_wait() {
  if constexpr (N == 0) asm volatile("s_waitcnt vmcnt(0)" ::: "memory");
  else if constexpr (N == 3) asm volatile("s_waitcnt vmcnt(3)" ::: "memory");
  else if constexpr (N == 6) asm volatile("s_waitcnt vmcnt(6)" ::: "memory");
  else if constexpr (N == 8) asm volatile("s_waitcnt vmcnt(8)" ::: "memory");
}

template <int N> __device__ __forceinline__ void lgkm_wait() {
  if constexpr (N == 0) asm volatile("s_waitcnt lgkmcnt(0)" ::: "memory");
  else if constexpr (N == 4) asm volatile("s_waitcnt lgkmcnt(4)" ::: "memory");
  else if constexpr (N == 8) asm volatile("s_waitcnt lgkmcnt(8)" ::: "memory");
}

__device__ __forceinline__ f32x16 mfma32(bf16x8 a, bf16x8 b, f32x16 c) {
  return __builtin_amdgcn_mfma_f32_32x32x16_bf16(a, b, c, 0, 0, 0);
}

// ---- fp32 -> bf16 convert ----
__global__ __launch_bounds__(256) void k_convert(const float* __restrict__ src,
                                                 u16* __restrict__ dst, long n) {
  long i = ((long)blockIdx.x * 256 + threadIdx.x) * 8;
  long stride = (long)gridDim.x * 256 * 8;
  for (; i < n; i += stride) {
    const float4 a = *(const float4*)(src + i);
    const float4 b = *(const float4*)(src + i + 4);
    u16x8 o;
    o[0] = f2bf(a.x); o[1] = f2bf(a.y); o[2] = f2bf(a.z); o[3] = f2bf(a.w);
    o[4] = f2bf(b.x); o[5] = f2bf(b.y); o[6] = f2bf(b.z); o[7] = f2bf(b.w);
    *(u16x8*)(dst + i) = o;
  }
}

// ---- w2 [E][F][H] fp32 -> w2t [E][H][F] bf16 ----
__global__ __launch_bounds__(256) void k_transpose_w2(const float* __restrict__ w2,
                                                      u16* __restrict__ w2t) {
  __shared__ float tile[32][33];
  const int ntH = H_DIM / 32;
  const int ntF = F_DIM / 32;
  int bid = blockIdx.x;
  int e = bid / (ntF * ntH);
  int r = bid % (ntF * ntH);
  int f0 = (r / ntH) * 32;
  int h0 = (r % ntH) * 32;
  const float* src = w2 + (size_t)e * F_DIM * H_DIM;
  u16* dst = w2t + (size_t)e * H_DIM * F_DIM;
  int col = threadIdx.x & 31;
  int row8 = threadIdx.x >> 5;
#pragma unroll
  for (int i = 0; i < 4; i++) {
    int row = row8 + i * 8;
    tile[row][col] = src[(size_t)(f0 + row) * H_DIM + h0 + col];
  }
  __syncthreads();
#pragma unroll
  for (int i = 0; i < 4; i++) {
    int row = row8 + i * 8;
    dst[(size_t)(h0 + row) * F_DIM + f0 + col] = f2bf(tile[col][row]);
  }
}

// ==== register-pipelined GEMM: C = A (MxK) * B^T (B is [N][K]), bf16 K-contig.
// BM x 256 tile, BK=64 (2 kh of 32), 8 waves (2x4), 512 thr, 32x32x16 MFMA.
// Phase q: [ds_read frags for phase q+1] [lgkm(just)] [stage] [MFMA(q) from
// regs read at q-1] [counted vmcnt] [barrier]. MFMA overlaps LDS delivery.
// MSPLIT=2: 4 phases/tile (kh x mh); MSPLIT=1: 2 phases/tile (kh).
template <int BM, int BN, int MSPLIT, int NTN, int NT, bool GELU>
__global__ __launch_bounds__(512, 2) void k_gemm(const u16* __restrict__ Ag,
                                                 const u16* __restrict__ Bg,
                                                 void* __restrict__ Cg) {
  constexpr int K = NT * 64;
  constexpr int WROWS = BM / 2;   // WM=2
  constexpr int WCOLS = 64;       // WN=4 (BN=256)
  constexpr int MF = WROWS / 32;
  constexpr int MFH = MF / MSPLIT;  // A-frags per phase (=2)
  constexpr int NF = 2;
  constexpr int NPH = 2 * MSPLIT;
  constexpr int PA = BM * 32;     // u16 per A piece
  constexpr int PB = BN * 32;
  constexpr int ABOFF = 4 * PA;
  constexpr int JA = BM / 128;    // stage instr/thread per A piece
  constexpr int JB = BN / 128;
  constexpr int NTOT = NTN * BN;
  constexpr int NTM = T_TOK / BM;
  constexpr int MT_PER_E = CAP / BM;
  constexpr int VMS = 3 * MSPLIT;               // steady counted vmcnt
  constexpr int VMP = (MSPLIT == 2) ? 8 : 3;    // prologue vmcnt

  __shared__ __align__(16) u16 lds[ABOFF + 4 * PB];

  const int tid = threadIdx.x;
  const int lane = tid & 63;
  const int wave = tid >> 6;
  const int wm = wave >> 2;       // 0..1
  const int wn = wave & 3;        // 0..3

  // bijective XCD swizzle (NWG%8==0) + 4x4 supertile decode
  constexpr int NWG = NTM * NTN;
  const int wg = ((int)blockIdx.x & 7) * (NWG / 8) + ((int)blockIdx.x >> 3);
  constexpr int NSN = NTN / 4;
  const int sup = wg >> 4, win = wg & 15;
  const int mt = (sup / NSN) * 4 + (win >> 2);
  const int nt_ = (sup % NSN) * 4 + (win & 3);

  const int e = mt / MT_PER_E;
  const u16* Ae = Ag + (size_t)mt * BM * K;
  const u16* Be = Bg + (size_t)e * NTOT * K + (size_t)nt_ * BN * K;

  // staging: LDS dest linear; source k-slot pre-swizzled (rule #21)
  const int srow = lane >> 2;
  const int kswz = (((lane & 3) ^ ((lane >> 3) & 3)) << 3);

  auto stageA = [&](int t, int kh) {
    u16* dst0 = &lds[((t & 1) * 2 + kh) * PA];
    const u16* src = Ae + (size_t)(t * 64 + kh * 32 + kswz);
#pragma unroll
    for (int j = 0; j < JA; ++j) {
      const int cr = (JA * wave + j) * 16 + srow;
      async_copy16(src + (size_t)cr * K, dst0 + (JA * wave + j) * 512);
    }
  };
  auto stageB = [&](int t, int kh) {
    u16* dst0 = &lds[ABOFF + ((t & 1) * 2 + kh) * PB];
    const u16* src = Be + (size_t)(t * 64 + kh * 32 + kswz);
#pragma unroll
    for (int j = 0; j < JB; ++j) {
      const int cr = (JB * wave + j) * 16 + srow;
      async_copy16(src + (size_t)cr * K, dst0 + (JB * wave + j) * 512);
    }
  };

  // frag reads (32x32x16): row = lane&31, k-subslot = lane>>5; XOR swizzle
  const int lane31 = lane & 31;
  const int khi = lane >> 5;
  const int swz = (lane >> 1) & 3;

  f32x16 acc[MF][NF] = {};
  bf16x8 afb[2][MFH][2];   // [buf][frag][kstep]
  bf16x8 bfb[2][NF][2];    // [kh-buf][frag][kstep]

  auto rdA = [&](auto BUF, auto MH, int tpar, int kh) {
    const u16* pa = &lds[(tpar * 2 + kh) * PA];
#pragma unroll
    for (int i = 0; i < MFH; ++i)
#pragma unroll
      for (int ks = 0; ks < 2; ++ks)
        afb[BUF.v][i][ks] = *(const bf16x8*)&pa[
            (wm * WROWS + (MH.v * MFH + i) * 32 + lane31) * 32 +
            (((khi + 2 * ks) ^ swz) << 3)];
  };
  auto rdB = [&](auto KHB, int tpar, int kh) {
    const u16* pb = &lds[ABOFF + (tpar * 2 + kh) * PB];
#pragma unroll
    for (int j = 0; j < NF; ++j)
#pragma unroll
      for (int ks = 0; ks < 2; ++ks)
        bfb[KHB.v][j][ks] = *(const bf16x8*)&pb[
            (wn * WCOLS + j * 32 + lane31) * 32 +
            (((khi + 2 * ks) ^ swz) << 3)];
  };

  // prologue: stage t0(kh0,kh1), t1(kh0); land t0kh0; read q0 frags.
  stageA(0, 0); stageB(0, 0); stageA(0, 1); stageB(0, 1);
  stageA(1, 0); stageB(1, 0);
  vm_wait<VMP>();
  wgbar();
  rdA(IC<0>{}, IC<0>{}, 0, 0);
  rdB(IC<0>{}, 0, 0);

  auto phaseF = [&](auto QC, int t, bool hasNext, bool has2, bool tailVM) {
    constexpr int Q = QC.v;
    constexpr int KH = (MSPLIT == 2) ? (Q >> 1) : Q;
    constexpr int MH = (MSPLIT == 2) ? (Q & 1) : 0;
    constexpr int QN = (Q + 1) % NPH;
    constexpr int KHN = (MSPLIT == 2) ? (QN >> 1) : QN;
    constexpr int MHN = (MSPLIT == 2) ? (QN & 1) : 0;
    constexpr bool RB = (MHN == 0);
    constexpr int ABW = (Q + 1) & 1, ABR = Q & 1;
    constexpr bool WRAP = (Q == NPH - 1);
    constexpr int NJUST = MFH * 2 + (RB ? NF * 2 : 0);
    const int tN = WRAP ? t + 1 : t;
    const bool doRead = !WRAP || hasNext;
    if (doRead) {
      rdA(IC<ABW>{}, IC<MHN>{}, tN & 1, KHN);
      if constexpr (RB) rdB(IC<KHN>{}, tN & 1, KHN);
      lgkm_wait<NJUST>();   // certifies phase q-1's reads delivered
    } else {
      lgkm_wait<0>();
    }
    // stage issue (after lgkm: overwritten pieces' reads certified delivered)
    if constexpr (MSPLIT == 2) {
      if constexpr (Q == 0) { if (hasNext) stageA(t + 1, 1); }
      else if constexpr (Q == 1) { if (hasNext) stageB(t + 1, 1); }
      else if constexpr (Q == 2) { if (has2) stageA(t + 2, 0); }
      else { if (has2) stageB(t + 2, 0); }
    } else {
      if constexpr (Q == 0) { if (hasNext) { stageA(t + 1, 1); stageB(t + 1, 1); } }
      else { if (has2) { stageA(t + 2, 0); stageB(t + 2, 0); } }
    }
    __builtin_amdgcn_sched_barrier(0);
    __builtin_amdgcn_s_setprio(1);
#pragma unroll
    for (int i = 0; i < MFH; ++i)
#pragma unroll
      for (int j = 0; j < NF; ++j)
#pragma unroll
        for (int ks = 0; ks < 2; ++ks)
          acc[MH * MFH + i][j] = mfma32(afb[ABR][i][ks], bfb[KH][j][ks],
                                        acc[MH * MFH + i][j]);
    __builtin_amdgcn_s_setprio(0);
    if constexpr (MSPLIT == 1 || (Q & 1) == 0) {
      if (tailVM) vm_wait<0>(); else vm_wait<VMS>();
    }
    wgbar();
  };

  for (int t = 0; t < NT; ++t) {
    const bool hasNext = (t < NT - 1);
    const bool has2 = (t < NT - 2);
    const bool tailVM = (t >= NT - 3);
    phaseF(IC<0>{}, t, hasNext, has2, tailVM);
    phaseF(IC<1>{}, t, hasNext, has2, tailVM);
    if constexpr (MSPLIT == 2) {
      phaseF(IC<2>{}, t, hasNext, has2, tailVM);
      phaseF(IC<3>{}, t, hasNext, has2, tailVM);
    }
  }

  // epilogue: 32x32 C/D layout (m74/m101): col=lane&31,
  // row = (reg&3) + 8*(reg>>2) + 4*(lane>>5)
  const size_t Crow0 = (size_t)mt * BM + wm * WROWS;
  const int Ccol0 = nt_ * BN + wn * WCOLS;
#pragma unroll
  for (int fm = 0; fm < MF; ++fm)
#pragma unroll
    for (int fn = 0; fn < NF; ++fn) {
      const int col = Ccol0 + fn * 32 + lane31;
#pragma unroll
      for (int r = 0; r < 16; ++r) {
        const size_t row = Crow0 + fm * 32 + (r & 3) + 8 * (r >> 2) + 4 * khi;
        if constexpr (GELU) {
          ((u16*)Cg)[row * NTOT + col] = f2bf(gelu_tanh(acc[fm][fn][r]));
        } else {
          ((float*)Cg)[row * NTOT + col] = acc[fm][fn][r];
        }
      }
    }
}

extern "C" void kernel_launch(void* const* d_in, const int* in_sizes, int n_in,
                              void* d_out, int out_size, void* d_ws, size_t ws_size,
                              hipStream_t stream) {
  const float* x = (const float*)d_in[0];
  const float* w1 = (const float*)d_in[1];
  const float* w2 = (const float*)d_in[2];

  u16* ws_x = (u16*)d_ws;                               // [T][H] bf16
  u16* ws_w1 = ws_x + (size_t)T_TOK * H_DIM;            // [E][F][H] bf16
  u16* ws_w2t = ws_w1 + (size_t)E_NUM * F_DIM * H_DIM;  // [E][H][F] bf16
  u16* ws_h = ws_w2t + (size_t)E_NUM * H_DIM * F_DIM;   // [T][F] bf16
  const size_t need =
      ((size_t)T_TOK * H_DIM + 2 * (size_t)E_NUM * F_DIM * H_DIM + (size_t)T_TOK * F_DIM) * 2;
  if (ws_size < need) return;

  k_convert<<<1024, 256, 0, stream>>>(x, ws_x, (long)T_TOK * H_DIM);
  k_convert<<<2048, 256, 0, stream>>>(w1, ws_w1, (long)E_NUM * F_DIM * H_DIM);
  k_transpose_w2<<<E_NUM * (F_DIM / 32) * (H_DIM / 32), 256, 0, stream>>>(w2, ws_w2t);

  // GEMM1: h = gelu(x_e @ w1_e^T) -> [T][F] bf16
  //   tile 256x256, MSPLIT=2 (4 phases), NTN=16, NT=16 -> 512 blocks
  k_gemm<256, 256, 2, 16, 16, true><<<512, 512, 0, stream>>>(ws_x, ws_w1, ws_h);
  // GEMM2: out = h_e @ w2t_e^T -> [T][H] f32
  //   tile 128x256, MSPLIT=1 (2 phases), NTN=4, NT=64 -> 256 blocks
  k_gemm<128, 256, 1, 4, 64, false><<<256, 512, 0, stream>>>(ws_h, ws_w2t, d_out);
}

// Round 5
// 261.976 us; speedup vs baseline: 1.0563x; 1.0563x over previous
//
#include <hip/hip_runtime.h>
#include <cstdint>
#include <cstddef>

typedef unsigned short u16;
typedef __attribute__((ext_vector_type(8))) short bf16x8;
typedef __attribute__((ext_vector_type(4))) float f32x4;
typedef __attribute__((ext_vector_type(8))) unsigned short u16x8;

#define T_TOK 8192
#define H_DIM 1024
#define F_DIM 4096
#define E_NUM 8
#define CAP (T_TOK / E_NUM)

template <int I> struct IC { static constexpr int v = I; };

__device__ __forceinline__ u16 f2bf(float f) {
  union { float f; uint32_t u; } v; v.f = f;
  uint32_t r = v.u + 0x7FFFu + ((v.u >> 16) & 1u);
  return (u16)(r >> 16);
}

__device__ __forceinline__ float gelu_tanh(float x) {
  float z2 = 1.5957691216057308f * (x + 0.044715f * x * x * x);
  float e = __expf(z2);
  return x * (1.0f - 1.0f / (e + 1.0f));
}

__device__ __forceinline__ void async_copy16(const void* gsrc, void* ldst) {
  __builtin_amdgcn_global_load_lds(
      (const __attribute__((address_space(1))) uint32_t*)gsrc,
      (__attribute__((address_space(3))) uint32_t*)ldst, 16, 0, 0);
}

__device__ __forceinline__ void wgbar() {
  asm volatile("" ::: "memory");
  __builtin_amdgcn_s_barrier();
  asm volatile("" ::: "memory");
}

template <int N> __device__ __forceinline__ void vm_wait() {
  if constexpr (N == 0) asm volatile("s_waitcnt vmcnt(0)" ::: "memory");
  else if constexpr (N == 3) asm volatile("s_waitcnt vmcnt(3)" ::: "memory");
  else if constexpr (N == 4) asm volatile("s_waitcnt vmcnt(4)" ::: "memory");
  else if constexpr (N == 6) asm volatile("s_waitcnt vmcnt(6)" ::: "memory");
  else if constexpr (N == 8) asm volatile("s_waitcnt vmcnt(8)" ::: "memory");
}

__device__ __forceinline__ void lgkm0() {
  asm volatile("s_waitcnt lgkmcnt(0)" ::: "memory");
}

// ---- fp32 -> bf16 convert ----
__global__ __launch_bounds__(256) void k_convert(const float* __restrict__ src,
                                                 u16* __restrict__ dst, long n) {
  long i = ((long)blockIdx.x * 256 + threadIdx.x) * 8;
  long stride = (long)gridDim.x * 256 * 8;
  for (; i < n; i += stride) {
    const float4 a = *(const float4*)(src + i);
    const float4 b = *(const float4*)(src + i + 4);
    u16x8 o;
    o[0] = f2bf(a.x); o[1] = f2bf(a.y); o[2] = f2bf(a.z); o[3] = f2bf(a.w);
    o[4] = f2bf(b.x); o[5] = f2bf(b.y); o[6] = f2bf(b.z); o[7] = f2bf(b.w);
    *(u16x8*)(dst + i) = o;
  }
}

// ---- w2 [E][F][H] fp32 -> w2t [E][H][F] bf16 ----
__global__ __launch_bounds__(256) void k_transpose_w2(const float* __restrict__ w2,
                                                      u16* __restrict__ w2t) {
  __shared__ float tile[32][33];
  const int ntH = H_DIM / 32;
  const int ntF = F_DIM / 32;
  int bid = blockIdx.x;
  int e = bid / (ntF * ntH);
  int r = bid % (ntF * ntH);
  int f0 = (r / ntH) * 32;
  int h0 = (r % ntH) * 32;
  const float* src = w2 + (size_t)e * F_DIM * H_DIM;
  u16* dst = w2t + (size_t)e * H_DIM * F_DIM;
  int col = threadIdx.x & 31;
  int row8 = threadIdx.x >> 5;
#pragma unroll
  for (int i = 0; i < 4; i++) {
    int row = row8 + i * 8;
    tile[row][col] = src[(size_t)(f0 + row) * H_DIM + h0 + col];
  }
  __syncthreads();
#pragma unroll
  for (int i = 0; i < 4; i++) {
    int row = row8 + i * 8;
    dst[(size_t)(h0 + row) * F_DIM + f0 + col] = f2bf(tile[col][row]);
  }
}

// ==== m201-style phase-locked GEMM: C = A (256xK) * B^T (B=[N][K]) bf16.
// 256xBN tile, BK=64 = 2 k-halves, 8 waves (WM x WN), 512 thr, 16x16x32 MFMA.
// Pieces: A[4]=[256][32] u16, B[4]=[BN][32]; piece id = (t&1)*2+kh.
// Phase: [ds_read frags][stage 2-3 instr][barrier][lgkm(0)][16 MFMA]
//        [counted vmcnt at kh-close][barrier].
// vmcnt before the phase-end barrier certifies (for ALL waves after the
// barrier) that the piece read 2 phases later has landed. Tail: 8->4->0.
// Addressing fully hoisted: stage ptrs & LDS frag offsets precomputed.
template <int BN, int WM, int WN, int NTN, int NT, bool GELU, int NPH>
__global__ __launch_bounds__(512, 2) void k_gemm(const u16* __restrict__ Ag,
                                                 const u16* __restrict__ Bg,
                                                 void* __restrict__ Cg) {
  constexpr int K = NT * 64;
  constexpr int WROWS = 256 / WM;
  constexpr int WCOLS = BN / WN;
  constexpr int FM = WROWS / 16;
  constexpr int FN = WCOLS / 16;
  constexpr int AH = (NPH == 4) ? FM / 2 : FM;   // A-frags per phase
  constexpr int PA = 256 * 32;   // u16 per A piece
  constexpr int PB = BN * 32;
  constexpr int ABOFF = 4 * PA;
  constexpr int JA = 2;          // stage instr/thread per A piece
  constexpr int JB = BN / 128;
  constexpr int VMS = 2 * (JA + JB);  // steady counted vmcnt
  constexpr int VMH = JA + JB;        // NT-2 tail
  constexpr int NTOT = NTN * BN;
  constexpr int NTM = 32;             // 8192/256

  __shared__ __align__(16) u16 lds[ABOFF + 4 * PB];

  const int tid = threadIdx.x;
  const int lane = tid & 63;
  const int wave = tid >> 6;
  const int wm = wave / WN;
  const int wn = wave % WN;

  // bijective XCD swizzle (NWG%8==0) + 4x4 supertile decode
  constexpr int NWG = NTM * NTN;
  const int wg = ((int)blockIdx.x & 7) * (NWG / 8) + ((int)blockIdx.x >> 3);
  constexpr int NSN = NTN / 4;
  const int sup = wg >> 4, win = wg & 15;
  const int mt = (sup / NSN) * 4 + (win >> 2);
  const int nt_ = (sup % NSN) * 4 + (win & 3);

  const int e = mt >> 2;  // CAP/256 = 4 m-tiles per expert
  const u16* Ae = Ag + (size_t)mt * 256 * K;
  const u16* Be = Bg + (size_t)e * NTOT * K + (size_t)nt_ * BN * K;

  // ---- hoisted stage addressing (LDS dest linear; src k-slot pre-swizzled) ----
  const int srow = lane >> 2;
  const int kswz = (((lane & 3) ^ ((lane >> 3) & 3)) << 3);
  const u16* srcA[JA];
  int dstA[JA];
  const u16* srcB[JB];
  int dstB[JB];
#pragma unroll
  for (int j = 0; j < JA; ++j) {
    const int cr = (JA * wave + j) * 16 + srow;
    srcA[j] = Ae + (size_t)cr * K + kswz;
    dstA[j] = (JA * wave + j) * 512;
  }
#pragma unroll
  for (int j = 0; j < JB; ++j) {
    const int cr = (JB * wave + j) * 16 + srow;
    srcB[j] = Be + (size_t)cr * K + kswz;
    dstB[j] = (JB * wave + j) * 512;
  }

  auto stageA = [&](int t, int kh) {
    const int pc = (t & 1) * 2 + kh;
    const int koff = t * 64 + kh * 32;
#pragma unroll
    for (int j = 0; j < JA; ++j)
      async_copy16(srcA[j] + koff, &lds[pc * PA + dstA[j]]);
  };
  auto stageB = [&](int t, int kh) {
    const int pc = (t & 1) * 2 + kh;
    const int koff = t * 64 + kh * 32;
#pragma unroll
    for (int j = 0; j < JB; ++j)
      async_copy16(srcB[j] + koff, &lds[ABOFF + pc * PB + dstB[j]]);
  };

  // ---- hoisted frag-read addressing (r2 zero-conflict layout) ----
  const int frow = lane & 15;
  const int fslot = (((lane >> 4) ^ ((lane >> 1) & 3)) << 3);
  const int aoff = (wm * WROWS + frow) * 32 + fslot;   // + frag*512
  const int boff = (wn * WCOLS + frow) * 32 + fslot;

  f32x4 acc[FM][FN] = {};
  bf16x8 af[AH], bf[FN];

  auto rdB = [&](int pc) {
    const u16* pb = &lds[ABOFF + pc * PB + boff];
#pragma unroll
    for (int j = 0; j < FN; ++j) bf[j] = *(const bf16x8*)(pb + j * 512);
  };
  auto rdA = [&](int pc, auto MH) {
    const u16* pa = &lds[pc * PA + aoff];
#pragma unroll
    for (int i = 0; i < AH; ++i)
      af[i] = *(const bf16x8*)(pa + (MH.v * AH + i) * 512);
  };
  auto mfmaC = [&](auto MH) {
    __builtin_amdgcn_s_setprio(1);
#pragma unroll
    for (int i = 0; i < AH; ++i)
#pragma unroll
      for (int j = 0; j < FN; ++j)
        acc[MH.v * AH + i][j] = __builtin_amdgcn_mfma_f32_16x16x32_bf16(
            af[i], bf[j], acc[MH.v * AH + i][j], 0, 0, 0);
    __builtin_amdgcn_s_setprio(0);
  };

  // prologue: 6 stage calls; drain to steady depth.
  stageA(0, 0); stageB(0, 0);
  stageA(0, 1); stageB(0, 1);
  stageA(1, 0); stageB(1, 0);
  vm_wait<VMS>();
  wgbar();

  for (int t = 0; t < NT; ++t) {
    const int p0 = (t & 1) * 2, p1 = p0 + 1;
    if constexpr (NPH == 4) {
      // q0: kh0, mh0
      rdB(p0); rdA(p0, IC<0>{});
      if (t < NT - 1) stageA(t + 1, 1);
      wgbar(); lgkm0();
      mfmaC(IC<0>{});
      wgbar();
      // q1: kh0, mh1
      rdA(p0, IC<1>{});
      if (t < NT - 1) stageB(t + 1, 1);
      wgbar(); lgkm0();
      mfmaC(IC<1>{});
      if (t < NT - 1) vm_wait<VMS>(); else vm_wait<0>();
      wgbar();
      // q2: kh1, mh0
      rdB(p1); rdA(p1, IC<0>{});
      if (t < NT - 2) stageA(t + 2, 0);
      wgbar(); lgkm0();
      mfmaC(IC<0>{});
      wgbar();
      // q3: kh1, mh1
      rdA(p1, IC<1>{});
      if (t < NT - 2) stageB(t + 2, 0);
      wgbar(); lgkm0();
      mfmaC(IC<1>{});
      if (t < NT - 2) vm_wait<VMS>();
      else if (t == NT - 2) vm_wait<VMH>();
      wgbar();
    } else {
      // q0: kh0
      rdB(p0); rdA(p0, IC<0>{});
      if (t < NT - 1) { stageA(t + 1, 1); stageB(t + 1, 1); }
      wgbar(); lgkm0();
      mfmaC(IC<0>{});
      if (t < NT - 1) vm_wait<VMS>(); else vm_wait<0>();
      wgbar();
      // q1: kh1
      rdB(p1); rdA(p1, IC<0>{});
      if (t < NT - 2) { stageA(t + 2, 0); stageB(t + 2, 0); }
      wgbar(); lgkm0();
      mfmaC(IC<0>{});
      if (t < NT - 2) vm_wait<VMS>();
      else if (t == NT - 2) vm_wait<VMH>();
      wgbar();
    }
  }

  // epilogue: C/D layout col=lane&15, row=(lane>>4)*4+reg
  const int lr = (lane >> 4) * 4;
  const int lc = lane & 15;
  const size_t Crow0 = (size_t)mt * 256 + wm * WROWS;
  const int Ccol0 = nt_ * BN + wn * WCOLS;
#pragma unroll
  for (int fm = 0; fm < FM; ++fm)
#pragma unroll
    for (int fn = 0; fn < FN; ++fn) {
      const int col = Ccol0 + fn * 16 + lc;
#pragma unroll
      for (int r = 0; r < 4; ++r) {
        const size_t row = Crow0 + fm * 16 + lr + r;
        if constexpr (GELU) {
          ((u16*)Cg)[row * NTOT + col] = f2bf(gelu_tanh(acc[fm][fn][r]));
        } else {
          ((float*)Cg)[row * NTOT + col] = acc[fm][fn][r];
        }
      }
    }
}

extern "C" void kernel_launch(void* const* d_in, const int* in_sizes, int n_in,
                              void* d_out, int out_size, void* d_ws, size_t ws_size,
                              hipStream_t stream) {
  const float* x = (const float*)d_in[0];
  const float* w1 = (const float*)d_in[1];
  const float* w2 = (const float*)d_in[2];

  u16* ws_x = (u16*)d_ws;                               // [T][H] bf16
  u16* ws_w1 = ws_x + (size_t)T_TOK * H_DIM;            // [E][F][H] bf16
  u16* ws_w2t = ws_w1 + (size_t)E_NUM * F_DIM * H_DIM;  // [E][H][F] bf16
  u16* ws_h = ws_w2t + (size_t)E_NUM * H_DIM * F_DIM;   // [T][F] bf16
  const size_t need =
      ((size_t)T_TOK * H_DIM + 2 * (size_t)E_NUM * F_DIM * H_DIM + (size_t)T_TOK * F_DIM) * 2;
  if (ws_size < need) return;

  k_convert<<<1024, 256, 0, stream>>>(x, ws_x, (long)T_TOK * H_DIM);
  k_convert<<<2048, 256, 0, stream>>>(w1, ws_w1, (long)E_NUM * F_DIM * H_DIM);
  k_transpose_w2<<<E_NUM * (F_DIM / 32) * (H_DIM / 32), 256, 0, stream>>>(w2, ws_w2t);

  // GEMM1: h = gelu(x_e @ w1_e^T) -> [T][F] bf16
  //   tile 256x256, waves 2x4, 4-phase, NTN=16, NT=16 -> 512 blocks
  k_gemm<256, 2, 4, 16, 16, true, 4><<<512, 512, 0, stream>>>(ws_x, ws_w1, ws_h);
  // GEMM2: out = h_e @ w2t_e^T -> [T][H] f32
  //   tile 256x128, waves 4x2, 2-phase, NTN=8, NT=64 -> 256 blocks
  k_gemm<128, 4, 2, 8, 64, false, 2><<<256, 512, 0, stream>>>(ws_h, ws_w2t, d_out);
}

// Round 7
// 261.509 us; speedup vs baseline: 1.0582x; 1.0018x over previous
//
#include <hip/hip_runtime.h>
#include <cstdint>
#include <cstddef>

typedef unsigned short u16;
typedef __attribute__((ext_vector_type(8))) short bf16x8;
typedef __attribute__((ext_vector_type(4))) float f32x4;
typedef __attribute__((ext_vector_type(8))) unsigned short u16x8;

#define T_TOK 8192
#define H_DIM 1024
#define F_DIM 4096
#define E_NUM 8
#define CAP (T_TOK / E_NUM)

template <int I> struct IC { static constexpr int v = I; };

__device__ __forceinline__ u16 f2bf(float f) {
  union { float f; uint32_t u; } v; v.f = f;
  uint32_t r = v.u + 0x7FFFu + ((v.u >> 16) & 1u);
  return (u16)(r >> 16);
}

__device__ __forceinline__ float gelu_tanh(float x) {
  float z2 = 1.5957691216057308f * (x + 0.044715f * x * x * x);
  float e = __expf(z2);
  return x * (1.0f - 1.0f / (e + 1.0f));
}

__device__ __forceinline__ void async_copy16(const void* gsrc, void* ldst) {
  __builtin_amdgcn_global_load_lds(
      (const __attribute__((address_space(1))) uint32_t*)gsrc,
      (__attribute__((address_space(3))) uint32_t*)ldst, 16, 0, 0);
}

__device__ __forceinline__ void wgbar() {
  asm volatile("" ::: "memory");
  __builtin_amdgcn_s_barrier();
  asm volatile("" ::: "memory");
}

template <int N> __device__ __forceinline__ void vm_wait() {
  static_assert(N == 0 || N == 3 || N == 6 || N == 8, "vm_wait: unsupported N");
  if constexpr (N == 0) asm volatile("s_waitcnt vmcnt(0)" ::: "memory");
  else if constexpr (N == 3) asm volatile("s_waitcnt vmcnt(3)" ::: "memory");
  else if constexpr (N == 6) asm volatile("s_waitcnt vmcnt(6)" ::: "memory");
  else if constexpr (N == 8) asm volatile("s_waitcnt vmcnt(8)" ::: "memory");
}

template <int N> __device__ __forceinline__ void lgkm_wait() {
  static_assert(N == 0 || N == 4 || N == 8, "lgkm_wait: unsupported N");
  if constexpr (N == 0) asm volatile("s_waitcnt lgkmcnt(0)" ::: "memory");
  else if constexpr (N == 4) asm volatile("s_waitcnt lgkmcnt(4)" ::: "memory");
  else if constexpr (N == 8) asm volatile("s_waitcnt lgkmcnt(8)" ::: "memory");
}

// ---- fp32 -> bf16 convert ----
__global__ __launch_bounds__(256) void k_convert(const float* __restrict__ src,
                                                 u16* __restrict__ dst, long n) {
  long i = ((long)blockIdx.x * 256 + threadIdx.x) * 8;
  long stride = (long)gridDim.x * 256 * 8;
  for (; i < n; i += stride) {
    const float4 a = *(const float4*)(src + i);
    const float4 b = *(const float4*)(src + i + 4);
    u16x8 o;
    o[0] = f2bf(a.x); o[1] = f2bf(a.y); o[2] = f2bf(a.z); o[3] = f2bf(a.w);
    o[4] = f2bf(b.x); o[5] = f2bf(b.y); o[6] = f2bf(b.z); o[7] = f2bf(b.w);
    *(u16x8*)(dst + i) = o;
  }
}

// ---- w2 [E][F][H] fp32 -> w2t [E][H][F] bf16 ----
__global__ __launch_bounds__(256) void k_transpose_w2(const float* __restrict__ w2,
                                                      u16* __restrict__ w2t) {
  __shared__ float tile[32][33];
  const int ntH = H_DIM / 32;
  const int ntF = F_DIM / 32;
  int bid = blockIdx.x;
  int e = bid / (ntF * ntH);
  int r = bid % (ntF * ntH);
  int f0 = (r / ntH) * 32;
  int h0 = (r % ntH) * 32;
  const float* src = w2 + (size_t)e * F_DIM * H_DIM;
  u16* dst = w2t + (size_t)e * H_DIM * F_DIM;
  int col = threadIdx.x & 31;
  int row8 = threadIdx.x >> 5;
#pragma unroll
  for (int i = 0; i < 4; i++) {
    int row = row8 + i * 8;
    tile[row][col] = src[(size_t)(f0 + row) * H_DIM + h0 + col];
  }
  __syncthreads();
#pragma unroll
  for (int i = 0; i < 4; i++) {
    int row = row8 + i * 8;
    dst[(size_t)(h0 + row) * F_DIM + f0 + col] = f2bf(tile[col][row]);
  }
}

// ==== register-pipelined phase-locked GEMM: C = A(256xK) * B^T (B=[N][K]) bf16.
// 256xBN tile, BK=64 = 2 kh, 8 waves (WM x WN), 512 thr, 16x16x32 MFMA.
// Pieces: A[4]=[256][32] u16, B[4]=[BN][32]; piece slot = (t&1)*2+kh.
// Phase q: [issue ds_reads for q+1 into frag buf^1] [stage] [lgkm(N_issued):
//   certifies q's operands (issued q-1, drained during q-1's MFMA)]
//   [sched_barrier] [MFMA(q) overlapping q+1's LDS drain] [vmcnt sched] [bar].
// ONE barrier per phase. vmcnt: NPH4 -> <6> at q0/q2-end; NPH2 -> <3> every
// phase-end; each wait certifies exactly the piece first-read one barrier
// later (FIFO-verified). Prologue drains to the steady invariant: NPH4 issues
// 12 and waits <8> (certifies t0kh0; t0kh1 certified at q0-end); NPH2 issues
// 9 and waits <3> (MUST certify t0kh0 AND t0kh1 -- q0 reads kh1 before any
// in-loop wait; <6> here was the r6 race). Tail t>=NT-3: vmcnt(0).
template <int BN, int WM, int WN, int NTN, int NT, bool GELU, int NPH>
__global__ __launch_bounds__(512, 2) void k_gemm(const u16* __restrict__ Ag,
                                                 const u16* __restrict__ Bg,
                                                 void* __restrict__ Cg) {
  constexpr int K = NT * 64;
  constexpr int WROWS = 256 / WM;
  constexpr int WCOLS = BN / WN;
  constexpr int FM = WROWS / 16;
  constexpr int FN = WCOLS / 16;
  constexpr int AH = (NPH == 4) ? FM / 2 : FM;   // A-frags per phase
  constexpr int PA = 256 * 32;   // u16 per A piece
  constexpr int PB = BN * 32;
  constexpr int ABOFF = 4 * PA;
  constexpr int JA = 2;          // stage instr/thread per A piece
  constexpr int JB = BN / 128;
  constexpr int VMS = (NPH == 4) ? (2 * JA + JB) : (JA + JB);  // 6 / 3
  constexpr int VMP = (NPH == 4) ? 8 : 3;                      // prologue
  constexpr int NTOT = NTN * BN;
  constexpr int NTM = 32;        // 8192/256

  __shared__ __align__(16) u16 lds[ABOFF + 4 * PB];

  const int tid = threadIdx.x;
  const int lane = tid & 63;
  const int wave = tid >> 6;
  const int wm = wave / WN;
  const int wn = wave % WN;

  // bijective XCD swizzle (NWG%8==0) + 4x4 supertile decode
  constexpr int NWG = NTM * NTN;
  const int wg = ((int)blockIdx.x & 7) * (NWG / 8) + ((int)blockIdx.x >> 3);
  constexpr int NSN = NTN / 4;
  const int sup = wg >> 4, win = wg & 15;
  const int mt = (sup / NSN) * 4 + (win >> 2);
  const int nt_ = (sup % NSN) * 4 + (win & 3);

  const int e = mt >> 2;  // CAP/256 = 4 m-tiles per expert
  const u16* Ae = Ag + (size_t)mt * 256 * K;
  const u16* Be = Bg + (size_t)e * NTOT * K + (size_t)nt_ * BN * K;

  // ---- hoisted stage addressing (LDS dest linear; src k-slot pre-swizzled) ----
  const int srow = lane >> 2;
  const int kswz = (((lane & 3) ^ ((lane >> 3) & 3)) << 3);
  const u16* srcA[JA];
  int dstA[JA];
  const u16* srcB[JB];
  int dstB[JB];
#pragma unroll
  for (int j = 0; j < JA; ++j) {
    const int cr = (JA * wave + j) * 16 + srow;
    srcA[j] = Ae + (size_t)cr * K + kswz;
    dstA[j] = (JA * wave + j) * 512;
  }
#pragma unroll
  for (int j = 0; j < JB; ++j) {
    const int cr = (JB * wave + j) * 16 + srow;
    srcB[j] = Be + (size_t)cr * K + kswz;
    dstB[j] = (JB * wave + j) * 512;
  }

  auto stageA = [&](int t, int kh) {
    const int pc = (t & 1) * 2 + kh;
    const int koff = t * 64 + kh * 32;
#pragma unroll
    for (int j = 0; j < JA; ++j)
      async_copy16(srcA[j] + koff, &lds[pc * PA + dstA[j]]);
  };
  auto stageB = [&](int t, int kh) {
    const int pc = (t & 1) * 2 + kh;
    const int koff = t * 64 + kh * 32;
#pragma unroll
    for (int j = 0; j < JB; ++j)
      async_copy16(srcB[j] + koff, &lds[ABOFF + pc * PB + dstB[j]]);
  };

  // ---- hoisted frag-read addressing (zero-conflict layout) ----
  const int frow = lane & 15;
  const int fslot = (((lane >> 4) ^ ((lane >> 1) & 3)) << 3);
  const int aoff = (wm * WROWS + frow) * 32 + fslot;   // + frag*512
  const int boff = (wn * WCOLS + frow) * 32 + fslot;

  f32x4 acc[FM][FN] = {};
  bf16x8 af2[2][AH], bf2[2][FN];   // compile-time-indexed frag double buffers

  auto rdB = [&](auto BUF, int pc) {
    const u16* pb = &lds[ABOFF + pc * PB + boff];
#pragma unroll
    for (int j = 0; j < FN; ++j) bf2[BUF.v][j] = *(const bf16x8*)(pb + j * 512);
  };
  auto rdA = [&](auto BUF, auto MH, int pc) {
    const u16* pa = &lds[pc * PA + aoff];
#pragma unroll
    for (int i = 0; i < AH; ++i)
      af2[BUF.v][i] = *(const bf16x8*)(pa + (MH.v * AH + i) * 512);
  };
  auto mfmaC = [&](auto AB, auto BB, auto MH) {
    __builtin_amdgcn_s_setprio(1);
#pragma unroll
    for (int i = 0; i < AH; ++i)
#pragma unroll
      for (int j = 0; j < FN; ++j)
        acc[MH.v * AH + i][j] = __builtin_amdgcn_mfma_f32_16x16x32_bf16(
            af2[AB.v][i], bf2[BB.v][j], acc[MH.v * AH + i][j], 0, 0, 0);
    __builtin_amdgcn_s_setprio(0);
  };

  // prologue: stage t0(kh0,kh1)+t1(kh0); certify per VMP; read q0 operands.
  stageA(0, 0); stageB(0, 0);
  stageA(0, 1); stageB(0, 1);
  stageA(1, 0); stageB(1, 0);
  vm_wait<VMP>();
  wgbar();
  rdB(IC<0>{}, 0); rdA(IC<0>{}, IC<0>{}, 0);

  for (int t = 0; t < NT; ++t) {
    const int p0 = (t & 1) * 2, p1 = p0 + 1;
    const int p0n = ((t + 1) & 1) * 2;
    const bool tailVM = (t >= NT - 3);
    if constexpr (NPH == 4) {
      // q0: MFMA p0/mh0 {af0,bf0}; read A(p0,mh1)->af1; stage A(t+1,1)
      rdA(IC<1>{}, IC<1>{}, p0);
      if (t < NT - 1) stageA(t + 1, 1);
      lgkm_wait<AH>();
      __builtin_amdgcn_sched_barrier(0);
      mfmaC(IC<0>{}, IC<0>{}, IC<0>{});
      if (tailVM) vm_wait<0>(); else vm_wait<VMS>();
      wgbar();
      // q1: MFMA p0/mh1 {af1,bf0}; read B(p1)->bf1, A(p1,mh0)->af0; stage B(t+1,1)
      rdB(IC<1>{}, p1); rdA(IC<0>{}, IC<0>{}, p1);
      if (t < NT - 1) stageB(t + 1, 1);
      lgkm_wait<AH + FN>();
      __builtin_amdgcn_sched_barrier(0);
      mfmaC(IC<1>{}, IC<0>{}, IC<1>{});
      wgbar();
      // q2: MFMA p1/mh0 {af0,bf1}; read A(p1,mh1)->af1; stage A(t+2,0)
      rdA(IC<1>{}, IC<1>{}, p1);
      if (t < NT - 2) stageA(t + 2, 0);
      lgkm_wait<AH>();
      __builtin_amdgcn_sched_barrier(0);
      mfmaC(IC<0>{}, IC<1>{}, IC<0>{});
      if (tailVM) vm_wait<0>(); else vm_wait<VMS>();
      wgbar();
      // q3: MFMA p1/mh1 {af1,bf1}; read next-tile B(p0n),A(p0n,mh0); stage B(t+2,0)
      if (t < NT - 1) { rdB(IC<0>{}, p0n); rdA(IC<0>{}, IC<0>{}, p0n); }
      if (t < NT - 2) stageB(t + 2, 0);
      if (t < NT - 1) lgkm_wait<AH + FN>(); else lgkm_wait<0>();
      __builtin_amdgcn_sched_barrier(0);
      mfmaC(IC<1>{}, IC<1>{}, IC<1>{});
      wgbar();
    } else {
      // q0: MFMA p0 {af0,bf0}; read p1 -> af1,bf1; stage A,B(t+1,1)
      rdB(IC<1>{}, p1); rdA(IC<1>{}, IC<0>{}, p1);
      if (t < NT - 1) { stageA(t + 1, 1); stageB(t + 1, 1); }
      lgkm_wait<AH + FN>();
      __builtin_amdgcn_sched_barrier(0);
      mfmaC(IC<0>{}, IC<0>{}, IC<0>{});
      if (tailVM) vm_wait<0>(); else vm_wait<VMS>();
      wgbar();
      // q1: MFMA p1 {af1,bf1}; read next-tile p0 -> af0,bf0; stage A,B(t+2,0)
      if (t < NT - 1) { rdB(IC<0>{}, p0n); rdA(IC<0>{}, IC<0>{}, p0n); }
      if (t < NT - 2) { stageA(t + 2, 0); stageB(t + 2, 0); }
      if (t < NT - 1) lgkm_wait<AH + FN>(); else lgkm_wait<0>();
      __builtin_amdgcn_sched_barrier(0);
      mfmaC(IC<1>{}, IC<1>{}, IC<0>{});
      if (tailVM) vm_wait<0>(); else vm_wait<VMS>();
      wgbar();
    }
  }

  // epilogue: C/D layout col=lane&15, row=(lane>>4)*4+reg
  const int lr = (lane >> 4) * 4;
  const int lc = lane & 15;
  const size_t Crow0 = (size_t)mt * 256 + wm * WROWS;
  const int Ccol0 = nt_ * BN + wn * WCOLS;
#pragma unroll
  for (int fm = 0; fm < FM; ++fm)
#pragma unroll
    for (int fn = 0; fn < FN; ++fn) {
      const int col = Ccol0 + fn * 16 + lc;
#pragma unroll
      for (int r = 0; r < 4; ++r) {
        const size_t row = Crow0 + fm * 16 + lr + r;
        if constexpr (GELU) {
          ((u16*)Cg)[row * NTOT + col] = f2bf(gelu_tanh(acc[fm][fn][r]));
        } else {
          ((float*)Cg)[row * NTOT + col] = acc[fm][fn][r];
        }
      }
    }
}

extern "C" void kernel_launch(void* const* d_in, const int* in_sizes, int n_in,
                              void* d_out, int out_size, void* d_ws, size_t ws_size,
                              hipStream_t stream) {
  const float* x = (const float*)d_in[0];
  const float* w1 = (const float*)d_in[1];
  const float* w2 = (const float*)d_in[2];

  u16* ws_x = (u16*)d_ws;                               // [T][H] bf16
  u16* ws_w1 = ws_x + (size_t)T_TOK * H_DIM;            // [E][F][H] bf16
  u16* ws_w2t = ws_w1 + (size_t)E_NUM * F_DIM * H_DIM;  // [E][H][F] bf16
  u16* ws_h = ws_w2t + (size_t)E_NUM * H_DIM * F_DIM;   // [T][F] bf16
  const size_t need =
      ((size_t)T_TOK * H_DIM + 2 * (size_t)E_NUM * F_DIM * H_DIM + (size_t)T_TOK * F_DIM) * 2;
  if (ws_size < need) return;

  k_convert<<<1024, 256, 0, stream>>>(x, ws_x, (long)T_TOK * H_DIM);
  k_convert<<<2048, 256, 0, stream>>>(w1, ws_w1, (long)E_NUM * F_DIM * H_DIM);
  k_transpose_w2<<<E_NUM * (F_DIM / 32) * (H_DIM / 32), 256, 0, stream>>>(w2, ws_w2t);

  // GEMM1: h = gelu(x_e @ w1_e^T) -> [T][F] bf16
  //   tile 256x256, waves 2x4, 4-phase, NTN=16, NT=16 -> 512 blocks
  k_gemm<256, 2, 4, 16, 16, true, 4><<<512, 512, 0, stream>>>(ws_x, ws_w1, ws_h);
  // GEMM2: out = h_e @ w2t_e^T -> [T][H] f32
  //   tile 256x128, waves 4x2, 2-phase, NTN=8, NT=64 -> 256 blocks
  k_gemm<128, 4, 2, 8, 64, false, 2><<<256, 512, 0, stream>>>(ws_h, ws_w2t, d_out);
}